// Round 2
// baseline (1210.918 us; speedup 1.0000x reference)
//
#include <hip/hip_runtime.h>
#include <cstdint>
#include <cstddef>

// ---------------------------------------------------------------------------
// DPN_88965952569844: out = relu(x@W1^T + b1) -> concat(x,h1) @ W2^T + b2
// B=4096, D_IN=4096, HID=16384, OUT=1000.  fp32 in/out, bf16 MFMA compute.
// R5: true 8-phase schedule (T3+T4+T5) on a 256^2 tile, BK=64:
//     - 2 LDS dbufs x 2 half-tiles (128x64) per matrix, 128 KiB total
//     - 4 phases per K-tile, each = {ds-read quadrant frags | stage 1-2
//       half-tiles -> barrier -> setprio(1) -> 16 MFMA -> setprio(0) -> barrier}
//     - quadrants (m0,n0),(m0,n1),(m1,n1),(m1,n0); B-n0 frags held in regs
//       P0->P3 so each LDS slot frees early enough for the issue plan:
//         h(t+1,Bhi)@P0, h(t+2,Blo)@P2, h(t+2,Alo)+h(t+2,Ahi)@P3
//     - single s_waitcnt vmcnt(6) per K-tile (FIFO-counted; vmcnt(0) only at
//       the NT-2 peel). Never drains in steady state.
//     - LDS chunk swizzle for BK=64: phys = q ^ (row&7), inverse applied on
//       the global source (global_load_lds writes linearly).
//     - GEMM1/GEMM2 split into separate symbols for distinct rocprof rows;
//       GEMM2 gets an intra-kz XCD swizzle (by-pairs per XCD).
// ---------------------------------------------------------------------------

using u16 = unsigned short;

typedef __bf16 bf16x8 __attribute__((ext_vector_type(8)));
typedef float  f32x4  __attribute__((ext_vector_type(4)));

#define GLOBAL_AS __attribute__((address_space(1)))
#define LDS_AS    __attribute__((address_space(3)))

__device__ __forceinline__ void async_load16(const void* gp, void* lp) {
    __builtin_amdgcn_global_load_lds((GLOBAL_AS void*)gp, (LDS_AS void*)lp, 16, 0, 0);
}

__device__ __forceinline__ u16 f2bf(float f) {
    union { float f; uint32_t u; } c; c.f = f;
    uint32_t u = c.u;
    u += 0x7FFFu + ((u >> 16) & 1u);   // round-to-nearest-even
    return (u16)(u >> 16);
}

// ---------------------------------------------------------------------------
// fp32 -> bf16 conversion kernels (unchanged)
// ---------------------------------------------------------------------------

__global__ void cvt_x_kernel(const float* __restrict__ x, u16* __restrict__ dst) {
    int idx = blockIdx.x * 256 + threadIdx.x;
    int row = idx >> 10;
    int c4  = (idx & 1023) << 2;
    float4 v = *(const float4*)&x[(size_t)row * 4096 + c4];
    ushort4 o;
    o.x = f2bf(v.x); o.y = f2bf(v.y); o.z = f2bf(v.z); o.w = f2bf(v.w);
    *(ushort4*)&dst[(size_t)row * 20480 + c4] = o;
}

__global__ void cvt_flat_kernel(const float* __restrict__ src, u16* __restrict__ dst) {
    int idx = blockIdx.x * 256 + threadIdx.x;
    float4 v = *(const float4*)&src[(size_t)idx * 4];
    ushort4 o;
    o.x = f2bf(v.x); o.y = f2bf(v.y); o.z = f2bf(v.z); o.w = f2bf(v.w);
    *(ushort4*)&dst[(size_t)idx * 4] = o;
}

__global__ void cvt_w2_kernel(const float* __restrict__ src, u16* __restrict__ dst) {
    int idx = blockIdx.x * 256 + threadIdx.x;
    int row = idx / 5120;
    int c4  = (idx % 5120) * 4;
    ushort4 o;
    if (row < 1000) {
        float4 v = *(const float4*)&src[(size_t)row * 20480 + c4];
        o.x = f2bf(v.x); o.y = f2bf(v.y); o.z = f2bf(v.z); o.w = f2bf(v.w);
    } else {
        o.x = 0; o.y = 0; o.z = 0; o.w = 0;
    }
    *(ushort4*)&dst[(size_t)row * 20480 + c4] = o;
}

// ---------------------------------------------------------------------------
// 8-phase 256x256 NT bf16 GEMM body.  C[M,N] = A[M,K'] * B[N,K']^T.
// EPI 0: C = bf16(relu(acc + bias[n])), C is u16*.  EPI 1: fp32 partials.
// SWZ 1: GEMM1 XCD swizzle for grid (64,16).  SWZ 2: GEMM2 intra-kz swizzle
// for grid (4,16,z).
// ---------------------------------------------------------------------------
#define BAR()  asm volatile("s_barrier" ::: "memory")

#define STG(P, L64, DST) do {                        \
        async_load16(P,       (DST) + dof);          \
        async_load16(P + L64, (DST) + 4096 + dof);   \
        P += 64; } while (0)

#define MFMA_Q(IB, JB, BF) do {                                               \
        __builtin_amdgcn_s_setprio(1);                                       \
        _Pragma("unroll")                                                    \
        for (int i = 0; i < 4; ++i)                                          \
            _Pragma("unroll")                                                \
            for (int j = 0; j < 2; ++j) {                                    \
                acc[(IB) + i][(JB) + j] =                                    \
                    __builtin_amdgcn_mfma_f32_16x16x32_bf16(                 \
                        aF[i][0], BF[j][0], acc[(IB) + i][(JB) + j], 0, 0, 0);\
                acc[(IB) + i][(JB) + j] =                                    \
                    __builtin_amdgcn_mfma_f32_16x16x32_bf16(                 \
                        aF[i][1], BF[j][1], acc[(IB) + i][(JB) + j], 0, 0, 0);\
            }                                                                \
        __builtin_amdgcn_s_setprio(0); } while (0)

template <int EPI, int SWZ>
__device__ __forceinline__
void gemm256p_body(const u16* __restrict__ A, int lda,
                   const u16* __restrict__ B, int ldb,
                   int K,
                   const float* __restrict__ bias,
                   void* __restrict__ Cout, int ldc, size_t c_slab) {
    // 2 bufs x 2 halves x [128 rows][8 chunks of 16B] per matrix
    __shared__ __align__(16) u16 As[32768];   // 64 KB
    __shared__ __align__(16) u16 Bs[32768];   // 64 KB

    const int tid = threadIdx.x;              // 0..511

    int bx = blockIdx.x, by = blockIdx.y;
    if (SWZ == 1) {
        // grid (64,16) = 1024 wgs; bijective (1024 % 8 == 0)
        const int lin    = by * (int)gridDim.x + bx;
        const int xcd    = lin & 7;
        const int wg     = xcd * 128 + (lin >> 3);
        const int panel  = wg >> 6;                  // 16 panels of 8x8 tiles
        const int within = wg & 63;
        bx = (panel >> 1) * 8 + (within & 7);
        by = (panel & 1) * 8 + (within >> 3);
    } else if (SWZ == 2) {
        // grid (4,16,z): swizzle within each kz-plane (64 wgs, 64 % 8 == 0)
        const int lin = by * (int)gridDim.x + bx;    // 0..63
        const int xcd = lin & 7;
        const int wg  = xcd * 8 + (lin >> 3);        // XCD gets by-pair x all bx
        bx = wg & 3;
        by = wg >> 2;
    }
    const int m0 = by * 256;
    const int n0 = bx * 256;
    const int kz = blockIdx.z;

    A += (size_t)kz * K;
    B += (size_t)kz * K;

    // ---- staging geometry: thread t covers chunks t and t+512 of each
    // 128x64 half-tile (row = c>>3, phys slot = c&7).  Swizzle: phys slot p
    // of row r holds global chunk p ^ (r&7)  (same XOR for r and r+64).
    const int srow = tid >> 3;                       // 0..63
    const int gq   = (tid & 7) ^ (srow & 7);
    const u16* pAlo = A + (size_t)(m0 + srow) * lda + gq * 8;
    const u16* pAhi = pAlo + (size_t)128 * lda;
    const u16* pBlo = B + (size_t)(n0 + srow) * ldb + gq * 8;
    const u16* pBhi = pBlo + (size_t)128 * ldb;
    const size_t a64 = (size_t)64 * lda;
    const size_t b64 = (size_t)64 * ldb;
    const int dof = tid * 8;                         // u16 units

    // ---- wave -> output subtile: 2 m-waves x 4 n-waves, 128x64 per wave
    const int wave = tid >> 6;
    const int wm   = wave >> 2;              // 0..1
    const int wn   = wave & 3;               // 0..3
    const int lane = tid & 63;
    const int ln16 = lane & 15;
    const int quad = lane >> 4;

    // fragment read offsets (u16): row R, k-slice ks, k-chunk q = ks*4+quad,
    // phys p = q ^ (R&7) = (ks*4+quad) ^ (ln16&7).  ks=1 addr = ks=0 addr ^ 32.
    const int p0 = (quad ^ (ln16 & 7)) * 8;
    int ao[8], bo[4];
#pragma unroll
    for (int i = 0; i < 8; ++i) {
        const int R = wm * 128 + i * 16 + ln16;
        ao[i] = (R >> 7) * 8192 + (R & 127) * 64 + p0;
    }
#pragma unroll
    for (int j = 0; j < 4; ++j) {
        const int R = wn * 64 + j * 16 + ln16;
        bo[j] = (R >> 7) * 8192 + (R & 127) * 64 + p0;
    }

    f32x4 acc[8][4] = {};
    bf16x8 aF[4][2], bn0[2][2], bn1[2][2];

    // ---- prologue: tile0 (4 half-tiles) + tile1 {Blo, Alo, Ahi} = 14 loads
    STG(pAlo, a64, As + 0);
    STG(pAhi, a64, As + 8192);
    STG(pBlo, b64, Bs + 0);
    STG(pBhi, b64, Bs + 8192);
    STG(pBlo, b64, Bs + 16384);          // h(1,Blo)
    STG(pAlo, a64, As + 16384);          // h(1,Alo)
    STG(pAhi, a64, As + 16384 + 8192);   // h(1,Ahi)
    asm volatile("s_waitcnt vmcnt(6)" ::: "memory");   // tile0 landed
    BAR();

    const int NT = K >> 6;               // BK = 64
    for (int t = 0; t < NT; ++t) {
        const int par  = (t & 1) << 14;  // tile t buffer base (u16)
        const int parn = 16384 - par;    // tile t+1 buffer base

        // ---- P0: quadrant (m0,n0); stage h(t+1,Bhi)
#pragma unroll
        for (int i = 0; i < 4; ++i) {
            aF[i][0] = *(const bf16x8*)&As[par + ao[i]];
            aF[i][1] = *(const bf16x8*)&As[par + (ao[i] ^ 32)];
        }
#pragma unroll
        for (int j = 0; j < 2; ++j) {
            bn0[j][0] = *(const bf16x8*)&Bs[par + bo[j]];
            bn0[j][1] = *(const bf16x8*)&Bs[par + (bo[j] ^ 32)];
        }
        if (t + 1 < NT) STG(pBhi, b64, Bs + parn + 8192);
        BAR();
        MFMA_Q(0, 0, bn0);
        BAR();

        // ---- P1: quadrant (m0,n1)
#pragma unroll
        for (int j = 0; j < 2; ++j) {
            bn1[j][0] = *(const bf16x8*)&Bs[par + bo[2 + j]];
            bn1[j][1] = *(const bf16x8*)&Bs[par + (bo[2 + j] ^ 32)];
        }
        BAR();
        MFMA_Q(0, 2, bn1);
        BAR();

        // ---- P2: quadrant (m1,n1); stage h(t+2,Blo) (slot freed at P1-end)
#pragma unroll
        for (int i = 0; i < 4; ++i) {
            aF[i][0] = *(const bf16x8*)&As[par + ao[4 + i]];
            aF[i][1] = *(const bf16x8*)&As[par + (ao[4 + i] ^ 32)];
        }
        if (t + 2 < NT) STG(pBlo, b64, Bs + par);
        BAR();
        MFMA_Q(4, 2, bn1);
        BAR();

        // ---- P3: quadrant (m1,n0) from regs; stage h(t+2,Alo/Ahi)
        if (t + 2 < NT) {
            STG(pAlo, a64, As + par);
            STG(pAhi, a64, As + par + 8192);
        }
        MFMA_Q(4, 0, bn0);
        // counted wait: retire through h(t+1,Bhi); keep 3 half-tiles in flight
        if (t < NT - 2)
            asm volatile("s_waitcnt vmcnt(6)" ::: "memory");
        else if (t == NT - 2)
            asm volatile("s_waitcnt vmcnt(0)" ::: "memory");
        BAR();
    }

    // ---- epilogue: C/D layout col = lane&15, row = quad*4 + reg (verified)
    if (EPI == 0) {
        u16* C = (u16*)Cout;
#pragma unroll
        for (int j = 0; j < 4; ++j) {
            const int col = n0 + wn * 64 + j * 16 + ln16;
            const float bv = bias[col];
#pragma unroll
            for (int i = 0; i < 8; ++i) {
#pragma unroll
                for (int r = 0; r < 4; ++r) {
                    const int row = m0 + wm * 128 + i * 16 + quad * 4 + r;
                    float v = acc[i][j][r] + bv;
                    v = v > 0.0f ? v : 0.0f;
                    C[(size_t)row * ldc + col] = f2bf(v);
                }
            }
        }
    } else {
        float* C = (float*)Cout + (size_t)kz * c_slab;
#pragma unroll
        for (int j = 0; j < 4; ++j) {
            const int col = n0 + wn * 64 + j * 16 + ln16;
#pragma unroll
            for (int i = 0; i < 8; ++i) {
#pragma unroll
                for (int r = 0; r < 4; ++r) {
                    const int row = m0 + wm * 128 + i * 16 + quad * 4 + r;
                    C[(size_t)row * ldc + col] = acc[i][j][r];
                }
            }
        }
    }
}

// separate symbols so rocprof rows are distinguishable
__global__ __launch_bounds__(512, 2)
void gemm1_kernel(const u16* __restrict__ A, int lda,
                  const u16* __restrict__ B, int ldb, int K,
                  const float* __restrict__ bias,
                  void* __restrict__ Cout, int ldc, size_t c_slab) {
    gemm256p_body<0, 1>(A, lda, B, ldb, K, bias, Cout, ldc, c_slab);
}

__global__ __launch_bounds__(512, 2)
void gemm2_kernel(const u16* __restrict__ A, int lda,
                  const u16* __restrict__ B, int ldb, int K,
                  const float* __restrict__ bias,
                  void* __restrict__ Cout, int ldc, size_t c_slab) {
    gemm256p_body<1, 2>(A, lda, B, ldb, K, bias, Cout, ldc, c_slab);
}

// out[m][n] = b2[n] + sum_{kz<4} part[kz][m][n], n < 1000 (float4 over n)
__global__ void reduce_out_kernel(const float* __restrict__ part,
                                  const float* __restrict__ b2,
                                  float* __restrict__ out) {
    const int idx = blockIdx.x * 256 + threadIdx.x;   // 4096*250
    const int m  = idx / 250;
    const int n4 = (idx % 250) * 4;
    const size_t slab = (size_t)4096 * 1024;
    const size_t off = (size_t)m * 1024 + n4;
    float4 s  = *(const float4*)&part[off];
    float4 p1 = *(const float4*)&part[slab + off];
    float4 p2 = *(const float4*)&part[2 * slab + off];
    float4 p3 = *(const float4*)&part[3 * slab + off];
    float4 bv = *(const float4*)&b2[n4];
    s.x += p1.x + p2.x + p3.x + bv.x;
    s.y += p1.y + p2.y + p3.y + bv.y;
    s.z += p1.z + p2.z + p3.z + bv.z;
    s.w += p1.w + p2.w + p3.w + bv.w;
    *(float4*)&out[(size_t)m * 1000 + n4] = s;
}

// ---------------------------------------------------------------------------

extern "C" void kernel_launch(void* const* d_in, const int* in_sizes, int n_in,
                              void* d_out, int out_size, void* d_ws, size_t ws_size,
                              hipStream_t stream) {
    const float* x  = (const float*)d_in[0];   // [4096, 4096]
    const float* W1 = (const float*)d_in[1];   // [16384, 4096]
    const float* b1 = (const float*)d_in[2];   // [16384]
    const float* W2 = (const float*)d_in[3];   // [1000, 20480]
    const float* b2 = (const float*)d_in[4];   // [1000]
    float* out = (float*)d_out;                // [4096, 1000]

    // workspace layout (bf16 elems)
    u16* concat = (u16*)d_ws;                        // [4096][20480]  167.8 MB
    u16* W1b = concat + (size_t)4096 * 20480;        // [16384][4096]  134.2 MB
    u16* W2b = W1b + (size_t)16384 * 4096;           // [1024][20480]   41.9 MB
    // partials reuse W1b region (free after GEMM1): 4*4096*1024 fp32 = 67 MB
    float* partials = (float*)W1b;

    cvt_x_kernel   <<<16384, 256, 0, stream>>>(x, concat);
    cvt_flat_kernel<<<65536, 256, 0, stream>>>(W1, W1b);
    cvt_w2_kernel  <<<20480, 256, 0, stream>>>(W2, W2b);

    // GEMM1: h1 = relu(x @ W1^T + b1) -> concat cols [4096, 20480)
    dim3 g1(16384 / 256, 4096 / 256, 1);   // (64, 16, 1) = 1024 wgs
    gemm1_kernel<<<g1, 512, 0, stream>>>(
        concat, 20480, W1b, 4096, 4096, b1, concat + 4096, 20480, 0);

    // GEMM2 split-K=4: partials[kz] = concat[:, kz*5120:(kz+1)*5120] @ W2^T
    dim3 g2(1024 / 256, 4096 / 256, 4);    // (4, 16, 4) = 256 wgs = 1/CU
    gemm2_kernel<<<g2, 512, 0, stream>>>(
        concat, 20480, W2b, 20480, 5120, nullptr, partials, 1024,
        (size_t)4096 * 1024);

    // out = b2 + sum partials
    reduce_out_kernel<<<4000, 256, 0, stream>>>(partials, b2, out);
}